// Round 2
// baseline (138.388 us; speedup 1.0000x reference)
//
#include <hip/hip_runtime.h>

#define ROWS 256
#define COLS 512
#define BATCH 512
#define NC 5
#define DEG 16
#define EPG (ROWS * DEG)     /* 4096 edges per graph  */
#define NPG (ROWS + COLS)    /* 768 nodes per graph   */
#define NTHREADS 256
#define EPSF 1e-7f

__device__ __forceinline__ float sigmoid_f(float a) {
    // 1/(1+e^-a); for a << 0, __expf(-a) -> inf -> result 0 (correct, no NaN)
    return 1.0f / (1.0f + __expf(-a));
}

__device__ __forceinline__ float tanh_f(float a) {
    // tanh(x) = 2*sigmoid(2x) - 1 ; saturates cleanly at +-1, no NaN
    return fmaf(2.0f, 1.0f / (1.0f + __expf(-2.0f * a)), -1.0f);
}

__global__ __launch_bounds__(NTHREADS) void gnni_kernel(
    const float* __restrict__ x,
    const int*   __restrict__ eidx,
    const float* __restrict__ w1_1, const float* __restrict__ b1_1,
    const float* __restrict__ w2_1, const float* __restrict__ b2_1,
    const float* __restrict__ wih_1, const float* __restrict__ whh_1,
    const float* __restrict__ bih_1, const float* __restrict__ bhh_1,
    const float* __restrict__ w1_2, const float* __restrict__ b1_2,
    const float* __restrict__ w2_2, const float* __restrict__ b2_2,
    const float* __restrict__ wih_2, const float* __restrict__ whh_2,
    const float* __restrict__ bih_2, const float* __restrict__ bhh_2,
    float* __restrict__ out)
{
    __shared__ unsigned int epack[EPG];   // src | (dst<<16), local ids
    __shared__ float hc[ROWS];            // check-node state
    __shared__ float hv[COLS];            // variable-node state
    __shared__ float m[COLS];             // message accumulator (shared by both phases)

    const int tid  = threadIdx.x;
    const int b    = blockIdx.x;
    const int base = b * NPG;
    const long ebase = (long)b * EPG;

    // ---- one-time loads: edges (coalesced) + initial node state ----
    for (int e = tid; e < EPG; e += NTHREADS) {
        unsigned s = (unsigned)(eidx[ebase + e] - base);                       // [0,256)
        unsigned d = (unsigned)(eidx[(long)BATCH * EPG + ebase + e] - base);   // [0,512)
        epack[e] = s | (d << 16);
    }
    for (int i = tid; i < NPG; i += NTHREADS) {
        float v = x[base + i];
        if (i < ROWS) hc[i] = v;
        else          hv[i - ROWS] = v;
    }
    __syncthreads();

    for (int it = 0; it < NC; ++it) {
        // =================== phase 1: check -> var ===================
        for (int v = tid; v < COLS; v += NTHREADS) m[v] = 0.0f;
        __syncthreads();

        for (int e = tid; e < EPG; e += NTHREADS) {
            unsigned p = epack[e];
            int s = (int)(p & 0xffffu);
            int d = (int)(p >> 16);
            float xj = hc[s];          // x_j = h[src]
            float xi = hv[d];          // x_i = h[dst]
            float msg = b2_1[0];
            #pragma unroll
            for (int k = 0; k < 10; ++k) {
                float hk = fmaf(w1_1[2 * k], xj, fmaf(w1_1[2 * k + 1], xi, b1_1[k]));
                hk = fmaxf(hk, 0.0f);
                msg = fmaf(w2_1[k], hk, msg);
            }
            atomicAdd(&m[d], msg);
        }
        __syncthreads();

        for (int v = tid; v < COLS; v += NTHREADS) {
            float xg = hv[v];
            float hx = m[v];
            float gi0 = fmaf(wih_1[0], xg, bih_1[0]);
            float gi1 = fmaf(wih_1[1], xg, bih_1[1]);
            float gi2 = fmaf(wih_1[2], xg, bih_1[2]);
            float gh0 = fmaf(whh_1[0], hx, bhh_1[0]);
            float gh1 = fmaf(whh_1[1], hx, bhh_1[1]);
            float gh2 = fmaf(whh_1[2], hx, bhh_1[2]);
            float r = sigmoid_f(gi0 + gh0);
            float z = sigmoid_f(gi1 + gh1);
            float n = tanh_f(fmaf(r, gh2, gi2));
            hv[v] = fmaf(1.0f - z, n, z * hx);
        }
        __syncthreads();

        // =================== phase 2: var -> check ===================
        for (int c = tid; c < ROWS; c += NTHREADS) m[c] = 0.0f;
        __syncthreads();

        for (int e = tid; e < EPG; e += NTHREADS) {
            unsigned p = epack[e];
            int s = (int)(p & 0xffffu);
            int d = (int)(p >> 16);
            float xj = hv[d];          // x_j = h[dst]
            float xi = hc[s];          // x_i = h[src]
            float msg = b2_2[0];
            #pragma unroll
            for (int k = 0; k < 10; ++k) {
                float hk = fmaf(w1_2[2 * k], xj, fmaf(w1_2[2 * k + 1], xi, b1_2[k]));
                hk = fmaxf(hk, 0.0f);
                msg = fmaf(w2_2[k], hk, msg);
            }
            atomicAdd(&m[s], msg);
        }
        __syncthreads();

        for (int c = tid; c < ROWS; c += NTHREADS) {
            float xg = hc[c];
            float hx = m[c];
            float gi0 = fmaf(wih_2[0], xg, bih_2[0]);
            float gi1 = fmaf(wih_2[1], xg, bih_2[1]);
            float gi2 = fmaf(wih_2[2], xg, bih_2[2]);
            float gh0 = fmaf(whh_2[0], hx, bhh_2[0]);
            float gh1 = fmaf(whh_2[1], hx, bhh_2[1]);
            float gh2 = fmaf(whh_2[2], hx, bhh_2[2]);
            float r = sigmoid_f(gi0 + gh0);
            float z = sigmoid_f(gi1 + gh1);
            float n = tanh_f(fmaf(r, gh2, gi2));
            hc[c] = fmaf(1.0f - z, n, z * hx);
        }
        __syncthreads();
    }

    // ---- epilogue: out = clip(sigmoid(-h), eps, 1-eps) ----
    for (int i = tid; i < NPG; i += NTHREADS) {
        float h = (i < ROWS) ? hc[i] : hv[i - ROWS];
        float sgm = 1.0f / (1.0f + __expf(h));   // sigmoid(-h)
        sgm = fminf(fmaxf(sgm, EPSF), 1.0f - EPSF);
        out[base + i] = sgm;
    }
}

extern "C" void kernel_launch(void* const* d_in, const int* in_sizes, int n_in,
                              void* d_out, int out_size, void* d_ws, size_t ws_size,
                              hipStream_t stream) {
    const float* x    = (const float*)d_in[0];
    const int*   eidx = (const int*)d_in[1];
    gnni_kernel<<<BATCH, NTHREADS, 0, stream>>>(
        x, eidx,
        (const float*)d_in[2],  (const float*)d_in[3],
        (const float*)d_in[4],  (const float*)d_in[5],
        (const float*)d_in[6],  (const float*)d_in[7],
        (const float*)d_in[8],  (const float*)d_in[9],
        (const float*)d_in[10], (const float*)d_in[11],
        (const float*)d_in[12], (const float*)d_in[13],
        (const float*)d_in[14], (const float*)d_in[15],
        (const float*)d_in[16], (const float*)d_in[17],
        (float*)d_out);
}

// Round 3
// 127.658 us; speedup vs baseline: 1.0841x; 1.0841x over previous
//
#include <hip/hip_runtime.h>

#define ROWS 256
#define COLS 512
#define BATCH 512
#define NC 5
#define DEG 16
#define EPG (ROWS * DEG)     /* 4096 edges per graph  */
#define NPG (ROWS + COLS)    /* 768 nodes per graph   */
#define NTHREADS 1024
#define EPT (EPG / NTHREADS) /* 4 edges per thread    */
#define EPSF 1e-7f

__device__ __forceinline__ float sigmoid_f(float a) {
    return 1.0f / (1.0f + __expf(-a));
}

__device__ __forceinline__ float tanh_f(float a) {
    return fmaf(2.0f, 1.0f / (1.0f + __expf(-2.0f * a)), -1.0f);
}

__global__ __launch_bounds__(NTHREADS) void gnni_kernel(
    const float* __restrict__ x,
    const int*   __restrict__ eidx,
    const float* __restrict__ w1_1, const float* __restrict__ b1_1,
    const float* __restrict__ w2_1, const float* __restrict__ b2_1,
    const float* __restrict__ wih_1, const float* __restrict__ whh_1,
    const float* __restrict__ bih_1, const float* __restrict__ bhh_1,
    const float* __restrict__ w1_2, const float* __restrict__ b1_2,
    const float* __restrict__ w2_2, const float* __restrict__ b2_2,
    const float* __restrict__ wih_2, const float* __restrict__ whh_2,
    const float* __restrict__ bih_2, const float* __restrict__ bhh_2,
    float* __restrict__ out)
{
    __shared__ float hc[ROWS];   // check-node state
    __shared__ float hv[COLS];   // variable-node state
    __shared__ float mv[COLS];   // messages -> variable nodes (phase 1)
    __shared__ float mc[ROWS];   // messages -> check nodes   (phase 2)

    const int tid  = threadIdx.x;
    const int b    = blockIdx.x;
    const int base = b * NPG;
    const long ebase = (long)b * EPG;

    // ---- edges: 4 per thread, kept in VGPRs for all 10 phases ----
    unsigned ep[EPT];
    #pragma unroll
    for (int i = 0; i < EPT; ++i) {
        int e = tid + i * NTHREADS;
        unsigned s = (unsigned)(eidx[ebase + e] - base);                       // [0,256)
        unsigned d = (unsigned)(eidx[(long)BATCH * EPG + ebase + e] - base);   // [0,512)
        ep[i] = s | (d << 16);
    }

    // ---- initial node state + zero mv (mc is zeroed inside the loop) ----
    if (tid < NPG) {
        float v = x[base + tid];
        if (tid < ROWS) hc[tid] = v;
        else            hv[tid - ROWS] = v;
    }
    if (tid < COLS) mv[tid] = 0.0f;
    __syncthreads();

    for (int it = 0; it < NC; ++it) {
        // ============ phase 1 edges: check -> var, accumulate into mv ============
        #pragma unroll
        for (int i = 0; i < EPT; ++i) {
            unsigned p = ep[i];
            int s = (int)(p & 0xffffu);
            int d = (int)(p >> 16);
            float xj = hc[s];          // x_j = h[src]
            float xi = hv[d];          // x_i = h[dst]
            float msg = b2_1[0];
            #pragma unroll
            for (int k = 0; k < 10; ++k) {
                float hk = fmaf(w1_1[2 * k], xj, fmaf(w1_1[2 * k + 1], xi, b1_1[k]));
                hk = fmaxf(hk, 0.0f);
                msg = fmaf(w2_1[k], hk, msg);
            }
            atomicAdd(&mv[d], msg);
        }
        __syncthreads();

        // ============ GRU update of var nodes; idle threads zero mc ============
        if (tid < COLS) {
            float xg = hv[tid];
            float hx = mv[tid];
            float gi0 = fmaf(wih_1[0], xg, bih_1[0]);
            float gi1 = fmaf(wih_1[1], xg, bih_1[1]);
            float gi2 = fmaf(wih_1[2], xg, bih_1[2]);
            float gh0 = fmaf(whh_1[0], hx, bhh_1[0]);
            float gh1 = fmaf(whh_1[1], hx, bhh_1[1]);
            float gh2 = fmaf(whh_1[2], hx, bhh_1[2]);
            float r = sigmoid_f(gi0 + gh0);
            float z = sigmoid_f(gi1 + gh1);
            float n = tanh_f(fmaf(r, gh2, gi2));
            hv[tid] = fmaf(1.0f - z, n, z * hx);
        } else if (tid - COLS < ROWS) {
            mc[tid - COLS] = 0.0f;     // threads 512..767
        }
        __syncthreads();

        // ============ phase 2 edges: var -> check, accumulate into mc ============
        #pragma unroll
        for (int i = 0; i < EPT; ++i) {
            unsigned p = ep[i];
            int s = (int)(p & 0xffffu);
            int d = (int)(p >> 16);
            float xj = hv[d];          // x_j = h[dst]
            float xi = hc[s];          // x_i = h[src]
            float msg = b2_2[0];
            #pragma unroll
            for (int k = 0; k < 10; ++k) {
                float hk = fmaf(w1_2[2 * k], xj, fmaf(w1_2[2 * k + 1], xi, b1_2[k]));
                hk = fmaxf(hk, 0.0f);
                msg = fmaf(w2_2[k], hk, msg);
            }
            atomicAdd(&mc[s], msg);
        }
        __syncthreads();

        // ============ GRU update of check nodes; idle threads zero mv ============
        if (tid < ROWS) {
            float xg = hc[tid];
            float hx = mc[tid];
            float gi0 = fmaf(wih_2[0], xg, bih_2[0]);
            float gi1 = fmaf(wih_2[1], xg, bih_2[1]);
            float gi2 = fmaf(wih_2[2], xg, bih_2[2]);
            float gh0 = fmaf(whh_2[0], hx, bhh_2[0]);
            float gh1 = fmaf(whh_2[1], hx, bhh_2[1]);
            float gh2 = fmaf(whh_2[2], hx, bhh_2[2]);
            float r = sigmoid_f(gi0 + gh0);
            float z = sigmoid_f(gi1 + gh1);
            float n = tanh_f(fmaf(r, gh2, gi2));
            hc[tid] = fmaf(1.0f - z, n, z * hx);
        } else if (tid - ROWS < COLS) {
            mv[tid - ROWS] = 0.0f;     // threads 256..767
        }
        __syncthreads();
    }

    // ---- epilogue: out = clip(sigmoid(-h), eps, 1-eps) ----
    if (tid < NPG) {
        float h = (tid < ROWS) ? hc[tid] : hv[tid - ROWS];
        float sgm = 1.0f / (1.0f + __expf(h));   // sigmoid(-h)
        sgm = fminf(fmaxf(sgm, EPSF), 1.0f - EPSF);
        out[base + tid] = sgm;
    }
}

extern "C" void kernel_launch(void* const* d_in, const int* in_sizes, int n_in,
                              void* d_out, int out_size, void* d_ws, size_t ws_size,
                              hipStream_t stream) {
    const float* x    = (const float*)d_in[0];
    const int*   eidx = (const int*)d_in[1];
    gnni_kernel<<<BATCH, NTHREADS, 0, stream>>>(
        x, eidx,
        (const float*)d_in[2],  (const float*)d_in[3],
        (const float*)d_in[4],  (const float*)d_in[5],
        (const float*)d_in[6],  (const float*)d_in[7],
        (const float*)d_in[8],  (const float*)d_in[9],
        (const float*)d_in[10], (const float*)d_in[11],
        (const float*)d_in[12], (const float*)d_in[13],
        (const float*)d_in[14], (const float*)d_in[15],
        (const float*)d_in[16], (const float*)d_in[17],
        (float*)d_out);
}

// Round 5
// 50.624 us; speedup vs baseline: 2.7337x; 2.5217x over previous
//
#include <hip/hip_runtime.h>

#define ROWS 256
#define COLS 512
#define BATCH 512
#define NC 5
#define DEG 16
#define EPG (ROWS * DEG)       /* 4096 edges per graph */
#define NPG (ROWS + COLS)      /* 768 nodes per graph  */
#define NTHREADS 512
#define EPT (EPG / NTHREADS)   /* 8 edges per thread   */
#define EPSF 1e-7f

typedef unsigned short u16;
typedef unsigned int   u32;

__device__ __forceinline__ float sigmoid_f(float a) {
    return 1.0f / (1.0f + __expf(-a));
}
__device__ __forceinline__ float tanh_f(float a) {
    return fmaf(2.0f, 1.0f / (1.0f + __expf(-2.0f * a)), -1.0f);
}

__global__ __launch_bounds__(NTHREADS) void gnni_kernel(
    const float* __restrict__ x,
    const int*   __restrict__ eidx,
    const float* __restrict__ w1_1, const float* __restrict__ b1_1,
    const float* __restrict__ w2_1, const float* __restrict__ b2_1,
    const float* __restrict__ wih_1, const float* __restrict__ whh_1,
    const float* __restrict__ bih_1, const float* __restrict__ bhh_1,
    const float* __restrict__ w1_2, const float* __restrict__ b1_2,
    const float* __restrict__ w2_2, const float* __restrict__ b2_2,
    const float* __restrict__ wih_2, const float* __restrict__ whh_2,
    const float* __restrict__ bih_2, const float* __restrict__ bhh_2,
    float* __restrict__ out)
{
    __shared__ u16  sc_src[EPG];      // src of edges, sorted by dst (phase 1 CSR payload)
    __shared__ u16  sc_dst[EPG];      // dst of edges, sorted by src (phase 2 CSR payload)
    __shared__ u16  ofs_v[COLS + 1];  // CSR offsets per var node
    __shared__ u16  ofs_c[ROWS + 1];  // CSR offsets per check node
    __shared__ float hc[ROWS];
    __shared__ float hv[COLS];
    __shared__ u32  cur[COLS];        // scratch: counts / scan / placement cursor

    const int tid  = threadIdx.x;
    const int b    = blockIdx.x;
    const int base = b * NPG;
    const long ebase = (long)b * EPG;

    // ---- load this thread's 8 edges into registers (coalesced) ----
    u32 ep[EPT];
    #pragma unroll
    for (int i = 0; i < EPT; ++i) {
        int e = tid + i * NTHREADS;
        u32 s = (u32)(eidx[ebase + e] - base);                        // [0,256)
        u32 d = (u32)(eidx[(long)BATCH * EPG + ebase + e] - base);    // [0,512)
        ep[i] = s | (d << 16);
    }

    // ================= counting sort #1: by dst (var) =================
    cur[tid] = 0;
    __syncthreads();
    #pragma unroll
    for (int i = 0; i < EPT; ++i) atomicAdd(&cur[ep[i] >> 16], 1u);
    __syncthreads();
    // inclusive Hillis-Steele scan over 512
    for (int st = 1; st < COLS; st <<= 1) {
        u32 t = (tid >= st) ? cur[tid - st] : 0u;
        __syncthreads();
        cur[tid] += t;
        __syncthreads();
    }
    ofs_v[tid + 1] = (u16)cur[tid];
    if (tid == 0) ofs_v[0] = 0;
    __syncthreads();
    cur[tid] = ofs_v[tid];            // exclusive prefix = placement cursor
    __syncthreads();
    #pragma unroll
    for (int i = 0; i < EPT; ++i) {
        u32 p = ep[i];
        u32 pos = atomicAdd(&cur[p >> 16], 1u);
        sc_src[pos] = (u16)(p & 0xffffu);
    }
    __syncthreads();

    // ================= counting sort #2: by src (check) =================
    if (tid < ROWS) cur[tid] = 0;
    __syncthreads();
    #pragma unroll
    for (int i = 0; i < EPT; ++i) atomicAdd(&cur[ep[i] & 0xffffu], 1u);
    __syncthreads();
    for (int st = 1; st < ROWS; st <<= 1) {
        u32 t = 0;
        if (tid < ROWS && tid >= st) t = cur[tid - st];
        __syncthreads();
        if (tid < ROWS) cur[tid] += t;
        __syncthreads();
    }
    if (tid < ROWS) ofs_c[tid + 1] = (u16)cur[tid];
    if (tid == 0) ofs_c[0] = 0;
    __syncthreads();
    if (tid < ROWS) cur[tid] = ofs_c[tid];
    __syncthreads();
    #pragma unroll
    for (int i = 0; i < EPT; ++i) {
        u32 p = ep[i];
        u32 pos = atomicAdd(&cur[p & 0xffffu], 1u);
        sc_dst[pos] = (u16)(p >> 16);
    }

    // ---- initial node state (thread tid owns var node tid) ----
    if (tid < ROWS) hc[tid] = x[base + tid];
    float hvreg = x[base + ROWS + tid];
    hv[tid] = hvreg;
    __syncthreads();

    for (int it = 0; it < NC; ++it) {
        // ===== phase 1: var owners gather check messages, GRU-update =====
        {
            const int beg = ofs_v[tid], end = ofs_v[tid + 1];
            const float xi = hvreg;
            float msum = 0.0f;
            for (int e = beg; e < end; ++e) {
                const int s = sc_src[e];
                const float xj = hc[s];
                float msg = b2_1[0];
                #pragma unroll
                for (int k = 0; k < 10; ++k) {
                    float hk = fmaf(w1_1[2 * k], xj, fmaf(w1_1[2 * k + 1], xi, b1_1[k]));
                    hk = fmaxf(hk, 0.0f);
                    msg = fmaf(w2_1[k], hk, msg);
                }
                msum += msg;
            }
            const float hx = msum;
            float gi0 = fmaf(wih_1[0], xi, bih_1[0]);
            float gi1 = fmaf(wih_1[1], xi, bih_1[1]);
            float gi2 = fmaf(wih_1[2], xi, bih_1[2]);
            float gh0 = fmaf(whh_1[0], hx, bhh_1[0]);
            float gh1 = fmaf(whh_1[1], hx, bhh_1[1]);
            float gh2 = fmaf(whh_1[2], hx, bhh_1[2]);
            float r = sigmoid_f(gi0 + gh0);
            float z = sigmoid_f(gi1 + gh1);
            float n = tanh_f(fmaf(r, gh2, gi2));
            hvreg = fmaf(1.0f - z, n, z * hx);
            hv[tid] = hvreg;
        }
        __syncthreads();

        // ===== phase 2: lane pairs per check node =====
        {
            const int c    = tid >> 1;
            const int half = tid & 1;
            const int beg = ofs_c[c], end = ofs_c[c + 1];
            const int h0  = (end - beg + 1) >> 1;
            const int lo  = half ? (beg + h0) : beg;
            const int hi  = half ? end : (beg + h0);
            const float xi = hc[c];
            float part = 0.0f;
            for (int e = lo; e < hi; ++e) {
                const int d = sc_dst[e];
                const float xj = hv[d];
                float msg = b2_2[0];
                #pragma unroll
                for (int k = 0; k < 10; ++k) {
                    float hk = fmaf(w1_2[2 * k], xj, fmaf(w1_2[2 * k + 1], xi, b1_2[k]));
                    hk = fmaxf(hk, 0.0f);
                    msg = fmaf(w2_2[k], hk, msg);
                }
                part += msg;
            }
            part += __shfl_xor(part, 1);
            if (half == 0) {
                const float hx = part;
                float gi0 = fmaf(wih_2[0], xi, bih_2[0]);
                float gi1 = fmaf(wih_2[1], xi, bih_2[1]);
                float gi2 = fmaf(wih_2[2], xi, bih_2[2]);
                float gh0 = fmaf(whh_2[0], hx, bhh_2[0]);
                float gh1 = fmaf(whh_2[1], hx, bhh_2[1]);
                float gh2 = fmaf(whh_2[2], hx, bhh_2[2]);
                float r = sigmoid_f(gi0 + gh0);
                float z = sigmoid_f(gi1 + gh1);
                float n = tanh_f(fmaf(r, gh2, gi2));
                hc[c] = fmaf(1.0f - z, n, z * hx);
            }
        }
        __syncthreads();
    }

    // ---- epilogue: out = clip(sigmoid(-h), eps, 1-eps) ----
    if (tid < ROWS) {
        float sgm = 1.0f / (1.0f + __expf(hc[tid]));
        out[base + tid] = fminf(fmaxf(sgm, EPSF), 1.0f - EPSF);
    }
    {
        float sgm = 1.0f / (1.0f + __expf(hvreg));
        out[base + ROWS + tid] = fminf(fmaxf(sgm, EPSF), 1.0f - EPSF);
    }
}

extern "C" void kernel_launch(void* const* d_in, const int* in_sizes, int n_in,
                              void* d_out, int out_size, void* d_ws, size_t ws_size,
                              hipStream_t stream) {
    const float* x    = (const float*)d_in[0];
    const int*   eidx = (const int*)d_in[1];
    gnni_kernel<<<BATCH, NTHREADS, 0, stream>>>(
        x, eidx,
        (const float*)d_in[2],  (const float*)d_in[3],
        (const float*)d_in[4],  (const float*)d_in[5],
        (const float*)d_in[6],  (const float*)d_in[7],
        (const float*)d_in[8],  (const float*)d_in[9],
        (const float*)d_in[10], (const float*)d_in[11],
        (const float*)d_in[12], (const float*)d_in[13],
        (const float*)d_in[14], (const float*)d_in[15],
        (const float*)d_in[16], (const float*)d_in[17],
        (float*)d_out);
}

// Round 7
// 42.821 us; speedup vs baseline: 3.2318x; 1.1822x over previous
//
#include <hip/hip_runtime.h>

#define ROWS 256
#define COLS 512
#define BATCH 512
#define NC 5
#define DEG 16
#define EPG (ROWS * DEG)       /* 4096 edges per graph */
#define NPG (ROWS + COLS)      /* 768 nodes per graph  */
#define NTHREADS 512
#define EPT (EPG / NTHREADS)   /* 8 edges per thread   */
#define EPSF 1e-7f

typedef unsigned short u16;
typedef unsigned int   u32;
typedef float v2f __attribute__((ext_vector_type(2)));

__device__ __forceinline__ float sigmoid_f(float a) {
    return 1.0f / (1.0f + __expf(-a));
}
__device__ __forceinline__ float tanh_f(float a) {
    return fmaf(2.0f, 1.0f / (1.0f + __expf(-2.0f * a)), -1.0f);
}

__global__ __launch_bounds__(NTHREADS) void gnni_kernel(
    const float* __restrict__ x,
    const int*   __restrict__ eidx,
    const float* __restrict__ w1_1, const float* __restrict__ b1_1,
    const float* __restrict__ w2_1, const float* __restrict__ b2_1,
    const float* __restrict__ wih_1, const float* __restrict__ whh_1,
    const float* __restrict__ bih_1, const float* __restrict__ bhh_1,
    const float* __restrict__ w1_2, const float* __restrict__ b1_2,
    const float* __restrict__ w2_2, const float* __restrict__ b2_2,
    const float* __restrict__ wih_2, const float* __restrict__ whh_2,
    const float* __restrict__ bih_2, const float* __restrict__ bhh_2,
    float* __restrict__ out)
{
    __shared__ u32  e1[EPG];          // (src | dst<<16), sorted by dst  (phase 1)
    __shared__ u32  e2[EPG];          // (src | dst<<16), sorted by src  (phase 2)
    __shared__ float msg[EPG];        // per-edge message buffer (both phases)
    __shared__ u16  ofs_v[COLS + 1];  // CSR offsets per var node
    __shared__ u16  ofs_c[ROWS + 1];  // CSR offsets per check node
    __shared__ float hc[ROWS];
    __shared__ float hv[COLS];
    __shared__ u32  cur[COLS];        // scratch: counts / scan / cursor

    const int tid  = threadIdx.x;
    const int b    = blockIdx.x;
    const int base = b * NPG;
    const long ebase = (long)b * EPG;

    // ---- load this thread's 8 edges into registers (coalesced) ----
    u32 ep[EPT];
    #pragma unroll
    for (int i = 0; i < EPT; ++i) {
        int e = tid + i * NTHREADS;
        u32 s = (u32)(eidx[ebase + e] - base);                        // [0,256)
        u32 d = (u32)(eidx[(long)BATCH * EPG + ebase + e] - base);    // [0,512)
        ep[i] = s | (d << 16);
    }

    // ================= counting sort #1: by dst (var) =================
    cur[tid] = 0;
    __syncthreads();
    #pragma unroll
    for (int i = 0; i < EPT; ++i) atomicAdd(&cur[ep[i] >> 16], 1u);
    __syncthreads();
    for (int st = 1; st < COLS; st <<= 1) {          // inclusive scan
        u32 t = (tid >= st) ? cur[tid - st] : 0u;
        __syncthreads();
        cur[tid] += t;
        __syncthreads();
    }
    ofs_v[tid + 1] = (u16)cur[tid];
    if (tid == 0) ofs_v[0] = 0;
    __syncthreads();
    cur[tid] = ofs_v[tid];
    __syncthreads();
    #pragma unroll
    for (int i = 0; i < EPT; ++i) {
        u32 p = ep[i];
        u32 pos = atomicAdd(&cur[p >> 16], 1u);
        e1[pos] = p;
    }
    __syncthreads();

    // ================= counting sort #2: by src (check) =================
    if (tid < ROWS) cur[tid] = 0;
    __syncthreads();
    #pragma unroll
    for (int i = 0; i < EPT; ++i) atomicAdd(&cur[ep[i] & 0xffffu], 1u);
    __syncthreads();
    for (int st = 1; st < ROWS; st <<= 1) {
        u32 t = 0;
        if (tid < ROWS && tid >= st) t = cur[tid - st];
        __syncthreads();
        if (tid < ROWS) cur[tid] += t;
        __syncthreads();
    }
    if (tid < ROWS) ofs_c[tid + 1] = (u16)cur[tid];
    if (tid == 0) ofs_c[0] = 0;
    __syncthreads();
    if (tid < ROWS) cur[tid] = ofs_c[tid];
    __syncthreads();
    #pragma unroll
    for (int i = 0; i < EPT; ++i) {
        u32 p = ep[i];
        u32 pos = atomicAdd(&cur[p & 0xffffu], 1u);
        e2[pos] = p;
    }

    // ---- weights into registers as float2 pairs (wave-uniform) ----
    v2f A1[5], C1[5], B1[5], W1[5], A2[5], C2[5], B2[5], W2[5];
    #pragma unroll
    for (int j = 0; j < 5; ++j) {
        A1[j] = (v2f){w1_1[4*j],     w1_1[4*j + 2]};
        C1[j] = (v2f){w1_1[4*j + 1], w1_1[4*j + 3]};
        B1[j] = (v2f){b1_1[2*j],     b1_1[2*j + 1]};
        W1[j] = (v2f){w2_1[2*j],     w2_1[2*j + 1]};
        A2[j] = (v2f){w1_2[4*j],     w1_2[4*j + 2]};
        C2[j] = (v2f){w1_2[4*j + 1], w1_2[4*j + 3]};
        B2[j] = (v2f){b1_2[2*j],     b1_2[2*j + 1]};
        W2[j] = (v2f){w2_2[2*j],     w2_2[2*j + 1]};
    }
    const float b2_1s = b2_1[0], b2_2s = b2_2[0];
    const v2f zero2 = (v2f){0.0f, 0.0f};

    // ---- initial node state (thread tid owns var node tid) ----
    if (tid < ROWS) hc[tid] = x[base + tid];
    float hvreg = x[base + ROWS + tid];
    hv[tid] = hvreg;
    __syncthreads();

    for (int it = 0; it < NC; ++it) {
        // ===== phase 1 pass A: edge-parallel MLP (balanced, 8 edges each) =====
        #pragma unroll
        for (int i = 0; i < EPT; ++i) {
            const int e = tid + i * NTHREADS;
            const u32 p = e1[e];
            const float xj = hc[p & 0xffffu];
            const float xi = hv[p >> 16];
            const v2f xj2 = (v2f){xj, xj}, xi2 = (v2f){xi, xi};
            v2f acc = (v2f){b2_1s, 0.0f};
            #pragma unroll
            for (int j = 0; j < 5; ++j) {
                v2f t = __builtin_elementwise_fma(C1[j], xi2, B1[j]);
                t = __builtin_elementwise_fma(A1[j], xj2, t);
                t = __builtin_elementwise_max(t, zero2);
                acc = __builtin_elementwise_fma(W1[j], t, acc);
            }
            msg[e] = acc.x + acc.y;
        }
        __syncthreads();

        // ===== phase 1 pass B: var owners segment-sum + GRU =====
        {
            const int beg = ofs_v[tid], end = ofs_v[tid + 1];
            float hx = 0.0f;
            for (int e = beg; e < end; ++e) hx += msg[e];
            const float xg = hvreg;
            float gi0 = fmaf(wih_1[0], xg, bih_1[0]);
            float gi1 = fmaf(wih_1[1], xg, bih_1[1]);
            float gi2 = fmaf(wih_1[2], xg, bih_1[2]);
            float gh0 = fmaf(whh_1[0], hx, bhh_1[0]);
            float gh1 = fmaf(whh_1[1], hx, bhh_1[1]);
            float gh2 = fmaf(whh_1[2], hx, bhh_1[2]);
            float r = sigmoid_f(gi0 + gh0);
            float z = sigmoid_f(gi1 + gh1);
            float n = tanh_f(fmaf(r, gh2, gi2));
            hvreg = fmaf(1.0f - z, n, z * hx);
            hv[tid] = hvreg;
        }
        __syncthreads();

        // ===== phase 2 pass A: edge-parallel MLP (uses fresh hv) =====
        #pragma unroll
        for (int i = 0; i < EPT; ++i) {
            const int e = tid + i * NTHREADS;
            const u32 p = e2[e];
            const float xi = hc[p & 0xffffu];
            const float xj = hv[p >> 16];
            const v2f xj2 = (v2f){xj, xj}, xi2 = (v2f){xi, xi};
            v2f acc = (v2f){b2_2s, 0.0f};
            #pragma unroll
            for (int j = 0; j < 5; ++j) {
                v2f t = __builtin_elementwise_fma(C2[j], xi2, B2[j]);
                t = __builtin_elementwise_fma(A2[j], xj2, t);
                t = __builtin_elementwise_max(t, zero2);
                acc = __builtin_elementwise_fma(W2[j], t, acc);
            }
            msg[e] = acc.x + acc.y;
        }
        __syncthreads();

        // ===== phase 2 pass B: lane-pair per check node, segment-sum + GRU =====
        {
            const int c    = tid >> 1;
            const int half = tid & 1;
            const int beg = ofs_c[c], end = ofs_c[c + 1];
            const int h0  = (end - beg + 1) >> 1;
            const int lo  = half ? (beg + h0) : beg;
            const int hi  = half ? end : (beg + h0);
            float part = 0.0f;
            for (int e = lo; e < hi; ++e) part += msg[e];
            part += __shfl_xor(part, 1);
            if (half == 0) {
                const float hx = part;
                const float xg = hc[c];
                float gi0 = fmaf(wih_2[0], xg, bih_2[0]);
                float gi1 = fmaf(wih_2[1], xg, bih_2[1]);
                float gi2 = fmaf(wih_2[2], xg, bih_2[2]);
                float gh0 = fmaf(whh_2[0], hx, bhh_2[0]);
                float gh1 = fmaf(whh_2[1], hx, bhh_2[1]);
                float gh2 = fmaf(whh_2[2], hx, bhh_2[2]);
                float r = sigmoid_f(gi0 + gh0);
                float z = sigmoid_f(gi1 + gh1);
                float n = tanh_f(fmaf(r, gh2, gi2));
                hc[c] = fmaf(1.0f - z, n, z * hx);
            }
        }
        __syncthreads();
    }

    // ---- epilogue: out = clip(sigmoid(-h), eps, 1-eps) ----
    if (tid < ROWS) {
        float sgm = 1.0f / (1.0f + __expf(hc[tid]));
        out[base + tid] = fminf(fmaxf(sgm, EPSF), 1.0f - EPSF);
    }
    {
        float sgm = 1.0f / (1.0f + __expf(hvreg));
        out[base + ROWS + tid] = fminf(fmaxf(sgm, EPSF), 1.0f - EPSF);
    }
}

extern "C" void kernel_launch(void* const* d_in, const int* in_sizes, int n_in,
                              void* d_out, int out_size, void* d_ws, size_t ws_size,
                              hipStream_t stream) {
    const float* x    = (const float*)d_in[0];
    const int*   eidx = (const int*)d_in[1];
    gnni_kernel<<<BATCH, NTHREADS, 0, stream>>>(
        x, eidx,
        (const float*)d_in[2],  (const float*)d_in[3],
        (const float*)d_in[4],  (const float*)d_in[5],
        (const float*)d_in[6],  (const float*)d_in[7],
        (const float*)d_in[8],  (const float*)d_in[9],
        (const float*)d_in[10], (const float*)d_in[11],
        (const float*)d_in[12], (const float*)d_in[13],
        (const float*)d_in[14], (const float*)d_in[15],
        (const float*)d_in[16], (const float*)d_in[17],
        (float*)d_out);
}